// Round 13
// baseline (291.070 us; speedup 1.0000x reference)
//
#include <hip/hip_runtime.h>

// Problem constants (match reference setup_inputs)
constexpr int  Bc    = 8;
constexpr int  Nc    = 2048;                      // power of two
constexpr int  DIN   = 5;
constexpr int  DHID  = 32;
constexpr int  NROWS = Bc * Nc;                   // 16384
constexpr long NF4   = (long)Bc * Nc * (Nc / 4);  // 8,388,608 float4 groups

typedef float vf4 __attribute__((ext_vector_type(4)));

// ---------------------------------------------------------------------------
// u[b, d, j] = sum_e M[d][e] * s[b, j, e],  M = Qw @ Kw^T (5x5)
// ---------------------------------------------------------------------------
__global__ __launch_bounds__(256) void u_precompute(
    const float* __restrict__ s, const float* __restrict__ Qw,
    const float* __restrict__ Kw, float* __restrict__ u)
{
    __shared__ float Msh[DIN * DIN];
    const int tid = threadIdx.x;
    if (tid < DIN * DIN) {
        const int d = tid / DIN, e = tid % DIN;
        float acc = 0.f;
        #pragma unroll
        for (int m = 0; m < DHID; ++m)
            acc = fmaf(Qw[d * DHID + m], Kw[e * DHID + m], acc);
        Msh[tid] = acc;
    }
    __syncthreads();
    const int g = blockIdx.x * 256 + tid;
    if (g >= NROWS) return;
    const int b = g >> 11;
    const int j = g & (Nc - 1);
    float sv[DIN];
    #pragma unroll
    for (int e = 0; e < DIN; ++e) sv[e] = s[(size_t)g * DIN + e];
    #pragma unroll
    for (int d = 0; d < DIN; ++d) {
        float acc = 0.f;
        #pragma unroll
        for (int e = 0; e < DIN; ++e) acc = fmaf(Msh[d * DIN + e], sv[e], acc);
        u[((size_t)b * DIN + d) * Nc + j] = acc;
    }
}

__global__ __launch_bounds__(256) void zero_sums(float* __restrict__ sums)
{
    const int i = blockIdx.x * 256 + threadIdx.x;
    if (i < NROWS) sums[i] = 0.f;
}

// ---------------------------------------------------------------------------
// Pass 1: pure grid-stride stream over G; per wave (64 lanes = 1 KB chunk,
// provably within one row since 512 float4/row), shuffle-reduce the partial
// and one atomicAdd into sums[row]. Independent iterations, deep pipeline.
// ---------------------------------------------------------------------------
__global__ __launch_bounds__(256) void pass1_sums(
    const float* __restrict__ s, const float* __restrict__ G,
    const float* __restrict__ u, float* __restrict__ sums, long gbs)
{
    const long stride = (long)gridDim.x * 256;
    const int  lane   = threadIdx.x & 63;
    for (long f = (long)blockIdx.x * 256 + threadIdx.x; f < NF4; f += stride) {
        const int r  = (int)(f >> 9);            // global row (512 float4/row)
        const int b  = r >> 11;
        const int i  = r & (Nc - 1);
        const int j0 = ((int)f & 511) * 4;

        const float4 g4 = *reinterpret_cast<const float4*>(
            G + (size_t)b * gbs + (size_t)i * Nc + j0);

        const float* sp = s + (size_t)r * DIN;   // wave-uniform broadcast
        const float* ub = u + (size_t)b * DIN * Nc;
        float vx = 0.f, vy = 0.f, vz = 0.f, vw = 0.f;
        #pragma unroll
        for (int d = 0; d < DIN; ++d) {
            const float sd = sp[d];
            const float4 u4 = *reinterpret_cast<const float4*>(ub + (size_t)d * Nc + j0);
            vx = fmaf(sd, u4.x, vx);
            vy = fmaf(sd, u4.y, vy);
            vz = fmaf(sd, u4.z, vz);
            vw = fmaf(sd, u4.w, vw);
        }
        float p = vx * vx * g4.x + vy * vy * g4.y + vz * vz * g4.z + vw * vw * g4.w;

        #pragma unroll
        for (int off = 32; off > 0; off >>= 1)
            p += __shfl_xor(p, off, 64);
        if (lane == 0) atomicAdd(&sums[r], p);
    }
}

// ---------------------------------------------------------------------------
// Pass 2: pure grid-stride stream; G is L3-hot from pass 1. Recompute t,
// scale by 1/(sum+1e-3), NT-store. No reduction, no coupling.
// ---------------------------------------------------------------------------
__global__ __launch_bounds__(256) void pass2_write(
    const float* __restrict__ s, const float* __restrict__ G,
    const float* __restrict__ u, const float* __restrict__ sums,
    float* __restrict__ out, long gbs)
{
    const long stride = (long)gridDim.x * 256;
    for (long f = (long)blockIdx.x * 256 + threadIdx.x; f < NF4; f += stride) {
        const int r  = (int)(f >> 9);
        const int b  = r >> 11;
        const int i  = r & (Nc - 1);
        const int j0 = ((int)f & 511) * 4;

        const float4 g4 = *reinterpret_cast<const float4*>(
            G + (size_t)b * gbs + (size_t)i * Nc + j0);

        const float* sp = s + (size_t)r * DIN;
        const float* ub = u + (size_t)b * DIN * Nc;
        float vx = 0.f, vy = 0.f, vz = 0.f, vw = 0.f;
        #pragma unroll
        for (int d = 0; d < DIN; ++d) {
            const float sd = sp[d];
            const float4 u4 = *reinterpret_cast<const float4*>(ub + (size_t)d * Nc + j0);
            vx = fmaf(sd, u4.x, vx);
            vy = fmaf(sd, u4.y, vy);
            vz = fmaf(sd, u4.z, vz);
            vw = fmaf(sd, u4.w, vw);
        }
        const float inv = 1.0f / (sums[r] + 0.001f);
        vf4 o;
        o.x = vx * vx * g4.x * inv;
        o.y = vy * vy * g4.y * inv;
        o.z = vz * vz * g4.z * inv;
        o.w = vw * vw * g4.w * inv;
        __builtin_nontemporal_store(o, reinterpret_cast<vf4*>(out + (f << 2)));
    }
}

// ---------------------------------------------------------------------------
// Fallback (no workspace): single-row blocks, M computed per block.
// ---------------------------------------------------------------------------
__global__ __launch_bounds__(256) void att_row_direct(
    const float* __restrict__ s, const float* __restrict__ G,
    const float* __restrict__ Qw, const float* __restrict__ Kw,
    float* __restrict__ out, long gbs)
{
    __shared__ float Msh[DIN * DIN];
    __shared__ float wpart[4];
    const int tid = threadIdx.x;
    if (tid < DIN * DIN) {
        const int d = tid / DIN, e = tid % DIN;
        float acc = 0.f;
        #pragma unroll
        for (int m = 0; m < DHID; ++m)
            acc = fmaf(Qw[d * DHID + m], Kw[e * DHID + m], acc);
        Msh[tid] = acc;
    }
    __syncthreads();

    const int row = blockIdx.x;
    const int b   = row >> 11;
    const int i   = row & (Nc - 1);

    float w[DIN];
    {
        float si[DIN];
        #pragma unroll
        for (int e = 0; e < DIN; ++e) si[e] = s[(size_t)row * DIN + e];
        #pragma unroll
        for (int d = 0; d < DIN; ++d) {
            float acc = 0.f;
            #pragma unroll
            for (int e = 0; e < DIN; ++e) acc = fmaf(si[e], Msh[e * DIN + d], acc);
            w[d] = acc;
        }
    }

    const float* gRow = G + (size_t)b * gbs + (size_t)i * Nc;
    const float* sb   = s + (size_t)b * Nc * DIN;
    float*       oRow = out + (size_t)row * Nc;

    float a[2][4];
    float lsum = 0.f;
    #pragma unroll
    for (int it = 0; it < 2; ++it) {
        const int j0 = it * 1024 + tid * 4;
        const float4 g4 = *reinterpret_cast<const float4*>(gRow + j0);
        float v[4];
        #pragma unroll
        for (int c = 0; c < 4; ++c) {
            const float* sj = sb + (size_t)(j0 + c) * DIN;
            float acc = 0.f;
            #pragma unroll
            for (int d = 0; d < DIN; ++d) acc = fmaf(w[d], sj[d], acc);
            v[c] = acc;
        }
        a[it][0] = v[0] * v[0] * g4.x;
        a[it][1] = v[1] * v[1] * g4.y;
        a[it][2] = v[2] * v[2] * g4.z;
        a[it][3] = v[3] * v[3] * g4.w;
        lsum += (a[it][0] + a[it][1]) + (a[it][2] + a[it][3]);
    }

    #pragma unroll
    for (int off = 32; off > 0; off >>= 1)
        lsum += __shfl_xor(lsum, off, 64);
    if ((tid & 63) == 0) wpart[tid >> 6] = lsum;
    __syncthreads();
    const float total = (wpart[0] + wpart[1]) + (wpart[2] + wpart[3]);
    const float inv = 1.0f / (total + 0.001f);

    #pragma unroll
    for (int it = 0; it < 2; ++it) {
        const int j0 = it * 1024 + tid * 4;
        vf4 o;
        o.x = a[it][0] * inv;
        o.y = a[it][1] * inv;
        o.z = a[it][2] * inv;
        o.w = a[it][3] * inv;
        __builtin_nontemporal_store(o, reinterpret_cast<vf4*>(oRow + j0));
    }
}

extern "C" void kernel_launch(void* const* d_in, const int* in_sizes, int n_in,
                              void* d_out, int out_size, void* d_ws, size_t ws_size,
                              hipStream_t stream)
{
    const float* s  = (const float*)d_in[0];
    const float* G  = (const float*)d_in[1];
    const float* Qw = (const float*)d_in[2];
    const float* Kw = (const float*)d_in[3];
    float* out = (float*)d_out;

    // Gmat may be [N,N] (broadcast) or [B,N,N]
    const long gbs = (in_sizes[1] == Nc * Nc) ? 0L : (long)Nc * Nc;

    // ws layout: sums[NROWS] | u[B*DIN*N]
    const size_t sumBytes = (size_t)NROWS * sizeof(float);
    const size_t uBytes   = (size_t)Bc * DIN * Nc * sizeof(float);

    if (ws_size >= sumBytes + uBytes) {
        float* sums = (float*)d_ws;
        float* u    = sums + NROWS;

        zero_sums<<<(NROWS + 255) / 256, 256, 0, stream>>>(sums);
        u_precompute<<<(NROWS + 255) / 256, 256, 0, stream>>>(s, Qw, Kw, u);
        pass1_sums<<<2048, 256, 0, stream>>>(s, G, u, sums, gbs);
        pass2_write<<<2048, 256, 0, stream>>>(s, G, u, sums, out, gbs);
    } else {
        att_row_direct<<<NROWS, 256, 0, stream>>>(s, G, Qw, Kw, out, gbs);
    }
}